// Round 2
// baseline (4018.056 us; speedup 1.0000x reference)
//
#include <hip/hip_runtime.h>

#define NPERM_C 250000
#define P_C     4000000          // slots = NPERM * 16
#define G_C     4096
#define NB1     1954             // ceil(P_C / 2048) for the scan

// ---------------------------------------------------------------------------
// repack weights[b,c,l] ((b*64+c)*16+l)  ->  WrT[l][c][b] = (l*64+c)*64+b
// so per-l chunks stage into LDS with coalesced float4 copies (no transpose).
// ---------------------------------------------------------------------------
__global__ void repack_w(const float* __restrict__ w, float* __restrict__ wrt) {
    int o = blockIdx.x * blockDim.x + threadIdx.x;   // o = (l*64+c)*64+b
    if (o >= 64 * 64 * 16) return;
    int b = o & 63, c = (o >> 6) & 63, l = o >> 12;
    wrt[o] = w[(b * 64 + c) * 16 + l];
}

// ---------------------------------------------------------------------------
// counting-sort stage 1: histogram of nnz per slot (both matrices).
// ---------------------------------------------------------------------------
__global__ __launch_bounds__(256) void hist(const int* __restrict__ r1,
                                            const int* __restrict__ r2,
                                            int* __restrict__ cnt) {
    int i = blockIdx.x * 256 + threadIdx.x;
    if (i < P_C)            atomicAdd(&cnt[r1[i]], 1);
    else if (i < 2 * P_C)   atomicAdd(&cnt[r2[i - P_C]], 1);
}

// ---------------------------------------------------------------------------
// counting-sort stage 2: exclusive scan over 4M counts (2048 elems / block).
// ---------------------------------------------------------------------------
__global__ __launch_bounds__(256) void scan_local(const int* __restrict__ cnt,
                                                  int* __restrict__ off,
                                                  int* __restrict__ bsum) {
    __shared__ int ts[256];
    int b = blockIdx.x, t = threadIdx.x;
    int base = b * 2048 + t * 8;
    int v[8]; int s = 0;
#pragma unroll
    for (int i = 0; i < 8; ++i) {
        int idx = base + i;
        v[i] = (idx < P_C) ? cnt[idx] : 0;
        s += v[i];
    }
    ts[t] = s;
    __syncthreads();
    for (int ofs = 1; ofs < 256; ofs <<= 1) {
        int xv = (t >= ofs) ? ts[t - ofs] : 0;
        __syncthreads();
        ts[t] += xv;
        __syncthreads();
    }
    int run = ts[t] - s;            // exclusive prefix of this thread
    if (t == 255) bsum[b] = ts[255];
#pragma unroll
    for (int i = 0; i < 8; ++i) {
        int idx = base + i;
        if (idx < P_C) off[idx] = run;
        run += v[i];
    }
}

__global__ void scan_top(int* __restrict__ bsum) {   // 1 block, 256 threads
    __shared__ int ts[256];
    int t = threadIdx.x;
    int base = t * 8;
    int v[8]; int s = 0;
#pragma unroll
    for (int i = 0; i < 8; ++i) {
        int idx = base + i;
        v[i] = (idx < NB1) ? bsum[idx] : 0;
        s += v[i];
    }
    ts[t] = s;
    __syncthreads();
    for (int ofs = 1; ofs < 256; ofs <<= 1) {
        int xv = (t >= ofs) ? ts[t - ofs] : 0;
        __syncthreads();
        ts[t] += xv;
        __syncthreads();
    }
    int run = ts[t] - s;
#pragma unroll
    for (int i = 0; i < 8; ++i) {
        int idx = base + i;
        if (idx < NB1) bsum[idx] = run;
        run += v[i];
    }
}

__global__ __launch_bounds__(256) void scan_add(int* __restrict__ off,
                                                const int* __restrict__ bsum,
                                                int* __restrict__ cur) {
    int b = blockIdx.x, t = threadIdx.x;
    int add = bsum[b];
    int base = b * 2048 + t * 8;
#pragma unroll
    for (int i = 0; i < 8; ++i) {
        int idx = base + i;
        if (idx < P_C) { int o = off[idx] + add; off[idx] = o; cur[idx] = o; }
    }
    if (b == 0 && t == 0) off[P_C] = 2 * P_C;
}

// ---------------------------------------------------------------------------
// counting-sort stage 3: scatter (col | src<<20, val) to sorted position.
// ---------------------------------------------------------------------------
__global__ __launch_bounds__(256) void scat(
        const int* __restrict__ r1, const int* __restrict__ c1, const float* __restrict__ v1,
        const int* __restrict__ r2, const int* __restrict__ c2, const float* __restrict__ v2,
        int* __restrict__ cur, unsigned* __restrict__ skey, float* __restrict__ sval) {
    int i = blockIdx.x * 256 + threadIdx.x;
    int row, col; float val; unsigned src;
    if (i < P_C)          { row = r1[i]; col = c1[i]; val = v1[i]; src = 0u; }
    else if (i < 2 * P_C) { int j = i - P_C; row = r2[j]; col = c2[j]; val = v2[j]; src = 1u << 20; }
    else return;
    int pos = atomicAdd(&cur[row], 1);
    skey[pos] = (unsigned)col | src;
    sval[pos] = val;
}

// ---------------------------------------------------------------------------
// degree scatter: only slot positions {0,5,10,15} are consumed.
// ---------------------------------------------------------------------------
__global__ __launch_bounds__(256) void scatter_deg(
        const int* __restrict__ row, const int* __restrict__ col,
        const float* __restrict__ val, const float* __restrict__ degs,
        float* __restrict__ degD) {
    int i = blockIdx.x * 256 + threadIdx.x;
    if (i >= P_C) return;
    int r = row[i];
    int pos = r & 15;
    if (pos == 0 || pos == 5 || pos == 10 || pos == 15)
        atomicAdd(&degD[(size_t)(r >> 4) * 4 + pos / 5], val[i] * degs[col[i]]);
}

// ---------------------------------------------------------------------------
// degree-gate MLP: dg = relu(deg4 @ W0^T + b0) @ W1^T + b1, 64 rows / block.
// ---------------------------------------------------------------------------
__global__ __launch_bounds__(256) void dg_gemm(
        const float* __restrict__ degD,
        const float* __restrict__ W0, const float* __restrict__ b0,
        const float* __restrict__ W1, const float* __restrict__ b1,
        float* __restrict__ dgb) {
    __shared__ float hidT[128][68];   // [h][r]
    __shared__ float w1T[128][68];    // [h][c]
    __shared__ float dloc[64][4];
    __shared__ float w0s[128][5];
    int t = threadIdx.x;
    int m0 = blockIdx.x * 64;

    {
        int r = t >> 2, j = t & 3;
        int gr = m0 + r; if (gr >= NPERM_C) gr = NPERM_C - 1;
        dloc[r][j] = degD[(size_t)gr * 4 + j];
    }
    if (t < 128) {
        w0s[t][0] = W0[t * 4 + 0]; w0s[t][1] = W0[t * 4 + 1];
        w0s[t][2] = W0[t * 4 + 2]; w0s[t][3] = W0[t * 4 + 3];
        w0s[t][4] = b0[t];
    }
    for (int s = 0; s < 32; ++s) {
        int idx = t + s * 256;
        w1T[idx & 127][idx >> 7] = W1[idx];
    }
    __syncthreads();
    for (int s = 0; s < 32; ++s) {
        int idx = t + s * 256;
        int h = idx & 127, r = idx >> 7;
        float v = w0s[h][4] + dloc[r][0] * w0s[h][0] + dloc[r][1] * w0s[h][1]
                            + dloc[r][2] * w0s[h][2] + dloc[r][3] * w0s[h][3];
        hidT[h][r] = fmaxf(v, 0.f);
    }
    __syncthreads();

    int tm = t >> 4, tn = t & 15;
    float acc[4][4] = {};
#pragma unroll 8
    for (int k = 0; k < 128; ++k) {
        float4 a = *reinterpret_cast<const float4*>(&hidT[k][tm * 4]);
        float4 b = *reinterpret_cast<const float4*>(&w1T[k][tn * 4]);
        acc[0][0] = fmaf(a.x, b.x, acc[0][0]); acc[0][1] = fmaf(a.x, b.y, acc[0][1]);
        acc[0][2] = fmaf(a.x, b.z, acc[0][2]); acc[0][3] = fmaf(a.x, b.w, acc[0][3]);
        acc[1][0] = fmaf(a.y, b.x, acc[1][0]); acc[1][1] = fmaf(a.y, b.y, acc[1][1]);
        acc[1][2] = fmaf(a.y, b.z, acc[1][2]); acc[1][3] = fmaf(a.y, b.w, acc[1][3]);
        acc[2][0] = fmaf(a.z, b.x, acc[2][0]); acc[2][1] = fmaf(a.z, b.y, acc[2][1]);
        acc[2][2] = fmaf(a.z, b.z, acc[2][2]); acc[2][3] = fmaf(a.z, b.w, acc[2][3]);
        acc[3][0] = fmaf(a.w, b.x, acc[3][0]); acc[3][1] = fmaf(a.w, b.y, acc[3][1]);
        acc[3][2] = fmaf(a.w, b.z, acc[3][2]); acc[3][3] = fmaf(a.w, b.w, acc[3][3]);
    }
    float bb[4] = {b1[tn * 4 + 0], b1[tn * 4 + 1], b1[tn * 4 + 2], b1[tn * 4 + 3]};
#pragma unroll
    for (int i = 0; i < 4; ++i) {
        int grow = m0 + tm * 4 + i;
        if (grow < NPERM_C) {
            float4 o = {acc[i][0] + bb[0], acc[i][1] + bb[1],
                        acc[i][2] + bb[2], acc[i][3] + bb[3]};
            *reinterpret_cast<float4*>(&dgb[(size_t)grow * 64 + tn * 4]) = o;
        }
    }
}

// ---------------------------------------------------------------------------
// Fused build + GEMM + epilogue. 128 perm-rows / block, 256 threads.
// Per l-chunk: build As[128][64] (reg-accumulate gathered feat rows, one
// ds_write), stage WrT[l] chunk, GEMM-accumulate acc[8][4] per thread.
// Epilogue: relu(h+bias) -> LDS, @ Wl^T + bl, * dg, store outb.
// Thread tile: rows tm+16i (i<8), cols tn+16j (j<4)  (conflict-free b128).
// ---------------------------------------------------------------------------
__global__ __launch_bounds__(256) void build_gemm(
        const unsigned* __restrict__ skey, const float* __restrict__ sval,
        const int* __restrict__ pOff,
        const float* __restrict__ x, const float* __restrict__ efeat,
        const float* __restrict__ WrT,
        const float* __restrict__ bias, const float* __restrict__ Wl,
        const float* __restrict__ bl, const float* __restrict__ dgb,
        float* __restrict__ outb) {
    __shared__ float As[128 * 68];   // [r][k], also reused for H
    __shared__ float Bs[64 * 68];    // [c][k]
    int t = threadIdx.x;
    int m0 = blockIdx.x * 128;
    int w = t >> 6, d = t & 63;
    int tm = t >> 4, tn = t & 15;
    float acc[8][4] = {};

    for (int l = 0; l < 16; ++l) {
        // stage W chunk: Bs[c][b] = WrT[(l*64+c)*64+b]
#pragma unroll
        for (int s = 0; s < 4; ++s) {
            int c = (t >> 4) + s * 16;
            int b4 = (t & 15) * 4;
            *reinterpret_cast<float4*>(&Bs[c * 68 + b4]) =
                *reinterpret_cast<const float4*>(&WrT[(size_t)(l * 64 + c) * 64 + b4]);
        }
        // build A chunk: wave w handles rows [w*32, w*32+32)
        for (int j = 0; j < 32; ++j) {
            int r = w * 32 + j;
            int n = m0 + r;
            float a = 0.f;
            if (n < NPERM_C) {
                int p = n * 16 + l;
                int s0 = pOff[p], e0 = pOff[p + 1];
                for (int e = s0; e < e0; ++e) {
                    unsigned k = skey[e];
                    float v = sval[e];
                    const float* f = (k & 0x100000u) ? efeat : x;
                    a = fmaf(v, f[(size_t)(k & 0xFFFFFu) * 64 + d], a);
                }
            }
            As[r * 68 + d] = a;
        }
        __syncthreads();
        // GEMM chunk
#pragma unroll 4
        for (int k = 0; k < 64; k += 4) {
            float4 b0 = *reinterpret_cast<const float4*>(&Bs[(tn     ) * 68 + k]);
            float4 b1 = *reinterpret_cast<const float4*>(&Bs[(tn + 16) * 68 + k]);
            float4 b2 = *reinterpret_cast<const float4*>(&Bs[(tn + 32) * 68 + k]);
            float4 b3 = *reinterpret_cast<const float4*>(&Bs[(tn + 48) * 68 + k]);
#pragma unroll
            for (int i = 0; i < 8; ++i) {
                float4 a = *reinterpret_cast<const float4*>(&As[(tm + 16 * i) * 68 + k]);
                acc[i][0] = fmaf(a.w, b0.w, fmaf(a.z, b0.z, fmaf(a.y, b0.y, fmaf(a.x, b0.x, acc[i][0]))));
                acc[i][1] = fmaf(a.w, b1.w, fmaf(a.z, b1.z, fmaf(a.y, b1.y, fmaf(a.x, b1.x, acc[i][1]))));
                acc[i][2] = fmaf(a.w, b2.w, fmaf(a.z, b2.z, fmaf(a.y, b2.y, fmaf(a.x, b2.x, acc[i][2]))));
                acc[i][3] = fmaf(a.w, b3.w, fmaf(a.z, b3.z, fmaf(a.y, b3.y, fmaf(a.x, b3.x, acc[i][3]))));
            }
        }
        __syncthreads();
    }

    // epilogue 1: H = relu(h + bias) into As region; stage Wl into Bs
    float bv[4];
#pragma unroll
    for (int j = 0; j < 4; ++j) bv[j] = bias[tn + 16 * j];
#pragma unroll
    for (int i = 0; i < 8; ++i)
#pragma unroll
        for (int j = 0; j < 4; ++j)
            As[(tm + 16 * i) * 68 + tn + 16 * j] = fmaxf(acc[i][j] + bv[j], 0.f);
#pragma unroll
    for (int s = 0; s < 4; ++s) {
        int c2 = (t >> 4) + s * 16;
        int k4 = (t & 15) * 4;
        *reinterpret_cast<float4*>(&Bs[c2 * 68 + k4]) =
            *reinterpret_cast<const float4*>(&Wl[c2 * 64 + k4]);
    }
    __syncthreads();

    float acc2[8][4] = {};
#pragma unroll 4
    for (int k = 0; k < 64; k += 4) {
        float4 b0 = *reinterpret_cast<const float4*>(&Bs[(tn     ) * 68 + k]);
        float4 b1 = *reinterpret_cast<const float4*>(&Bs[(tn + 16) * 68 + k]);
        float4 b2 = *reinterpret_cast<const float4*>(&Bs[(tn + 32) * 68 + k]);
        float4 b3 = *reinterpret_cast<const float4*>(&Bs[(tn + 48) * 68 + k]);
#pragma unroll
        for (int i = 0; i < 8; ++i) {
            float4 a = *reinterpret_cast<const float4*>(&As[(tm + 16 * i) * 68 + k]);
            acc2[i][0] = fmaf(a.w, b0.w, fmaf(a.z, b0.z, fmaf(a.y, b0.y, fmaf(a.x, b0.x, acc2[i][0]))));
            acc2[i][1] = fmaf(a.w, b1.w, fmaf(a.z, b1.z, fmaf(a.y, b1.y, fmaf(a.x, b1.x, acc2[i][1]))));
            acc2[i][2] = fmaf(a.w, b2.w, fmaf(a.z, b2.z, fmaf(a.y, b2.y, fmaf(a.x, b2.x, acc2[i][2]))));
            acc2[i][3] = fmaf(a.w, b3.w, fmaf(a.z, b3.z, fmaf(a.y, b3.y, fmaf(a.x, b3.x, acc2[i][3]))));
        }
    }
    float blv[4];
#pragma unroll
    for (int j = 0; j < 4; ++j) blv[j] = bl[tn + 16 * j];
#pragma unroll
    for (int i = 0; i < 8; ++i) {
        int grow = m0 + tm + 16 * i;
        if (grow < NPERM_C) {
#pragma unroll
            for (int j = 0; j < 4; ++j) {
                size_t idx = (size_t)grow * 64 + tn + 16 * j;
                float g = dgb[idx];               // read before aliased write
                outb[idx] = (acc2[i][j] + blv[j]) * g;
            }
        }
    }
}

// ---------------------------------------------------------------------------
// pooling scatter, one wave per nnz.
// ---------------------------------------------------------------------------
__global__ __launch_bounds__(256) void pool_scatter(
        const int* __restrict__ prow, const int* __restrict__ pcol,
        const float* __restrict__ pval, const float* __restrict__ outb,
        float* __restrict__ out) {
    int t = blockIdx.x * 256 + threadIdx.x;
    int i = t >> 6, d = t & 63;
    if (i >= NPERM_C) return;
    int r = prow[i], c = pcol[i];
    float v = pval[i];
    atomicAdd(&out[(size_t)r * 64 + d], v * outb[(size_t)c * 64 + d]);
}

extern "C" void kernel_launch(void* const* d_in, const int* in_sizes, int n_in,
                              void* d_out, int out_size, void* d_ws, size_t ws_size,
                              hipStream_t stream) {
    const float* x       = (const float*)d_in[0];
    const float* efeat   = (const float*)d_in[1];
    const float* degs    = (const float*)d_in[2];
    const int*   n2p_row = (const int*)d_in[3];
    const int*   n2p_col = (const int*)d_in[4];
    const float* n2p_val = (const float*)d_in[5];
    const int*   e2p_row = (const int*)d_in[6];
    const int*   e2p_col = (const int*)d_in[7];
    const float* e2p_val = (const float*)d_in[8];
    const int*   pool_row = (const int*)d_in[9];
    const int*   pool_col = (const int*)d_in[10];
    const float* pool_val = (const float*)d_in[11];
    const float* weights = (const float*)d_in[12];
    const float* bias    = (const float*)d_in[13];
    const float* W0      = (const float*)d_in[14];
    const float* b0      = (const float*)d_in[15];
    const float* W1      = (const float*)d_in[16];
    const float* b1      = (const float*)d_in[17];
    const float* Wl      = (const float*)d_in[18];
    const float* bl      = (const float*)d_in[19];
    float* out = (float*)d_out;

    // workspace layout (4-byte elems):
    // skey[8M] | sval[8M] | pOff[4M+64] | pCur[4M] | pCnt[4M] | bsum[2048]
    // | WrT[65536] | degD[1M] | dgb/outb[16M]   total ~45.07M elems ~172 MB
    unsigned* skey = (unsigned*)d_ws;
    float*    sval = (float*)(skey + 8000000);
    int*      pOff = (int*)(sval + 8000000);
    int*      pCur = pOff + 4000064;
    int*      pCnt = pCur + 4000000;
    int*      bsum = pCnt + 4000000;
    float*    WrT  = (float*)(bsum + 2048);
    float*    degD = WrT + 65536;
    float*    dgb  = degD + 1000000;   // aliased as outb
    float*    outb = dgb;

    size_t need = (size_t)(8000000 + 8000000 + 4000064 + 4000000 + 4000000 +
                           2048 + 65536 + 1000000 + 16000000) * 4;
    if (ws_size < need) {
        // insufficient workspace: return cleanly (wrong answer, not a fault)
        hipMemsetAsync(d_out, 0, (size_t)out_size * 4, stream);
        return;
    }

    hipMemsetAsync(pCnt, 0, (size_t)P_C * 4, stream);
    hipMemsetAsync(degD, 0, (size_t)NPERM_C * 4 * 4, stream);
    hipMemsetAsync(out, 0, (size_t)G_C * 64 * 4, stream);

    repack_w<<<256, 256, 0, stream>>>(weights, WrT);
    hist<<<31250, 256, 0, stream>>>(n2p_row, e2p_row, pCnt);
    scan_local<<<NB1, 256, 0, stream>>>(pCnt, pOff, bsum);
    scan_top<<<1, 256, 0, stream>>>(bsum);
    scan_add<<<NB1, 256, 0, stream>>>(pOff, bsum, pCur);
    scat<<<31250, 256, 0, stream>>>(n2p_row, n2p_col, n2p_val,
                                    e2p_row, e2p_col, e2p_val,
                                    pCur, skey, sval);
    scatter_deg<<<15625, 256, 0, stream>>>(n2p_row, n2p_col, n2p_val, degs, degD);
    dg_gemm<<<(NPERM_C + 63) / 64, 256, 0, stream>>>(degD, W0, b0, W1, b1, dgb);
    build_gemm<<<(NPERM_C + 127) / 128, 256, 0, stream>>>(
        skey, sval, pOff, x, efeat, WrT, bias, Wl, bl, dgb, outb);
    pool_scatter<<<62500, 256, 0, stream>>>(pool_row, pool_col, pool_val, outb, out);
}

// Round 3
// 2992.948 us; speedup vs baseline: 1.3425x; 1.3425x over previous
//
#include <hip/hip_runtime.h>

#define NPERM_C 250000
#define P_C     4000000          // slots = NPERM * 16
#define G_C     4096
#define NB1     1954             // ceil(P_C / 2048) for the scan

// ---------------------------------------------------------------------------
// repack weights[b,c,l] ((b*64+c)*16+l)  ->  WrT[l][c][b] = (l*64+c)*64+b
// ---------------------------------------------------------------------------
__global__ void repack_w(const float* __restrict__ w, float* __restrict__ wrt) {
    int o = blockIdx.x * blockDim.x + threadIdx.x;   // o = (l*64+c)*64+b
    if (o >= 64 * 64 * 16) return;
    int b = o & 63, c = (o >> 6) & 63, l = o >> 12;
    wrt[o] = w[(b * 64 + c) * 16 + l];
}

// ---------------------------------------------------------------------------
// counting-sort stage 1: histogram of nnz per slot (both matrices).
// ---------------------------------------------------------------------------
__global__ __launch_bounds__(256) void hist(const int* __restrict__ r1,
                                            const int* __restrict__ r2,
                                            int* __restrict__ cnt) {
    int i = blockIdx.x * 256 + threadIdx.x;
    if (i < P_C)            atomicAdd(&cnt[r1[i]], 1);
    else if (i < 2 * P_C)   atomicAdd(&cnt[r2[i - P_C]], 1);
}

// ---------------------------------------------------------------------------
// counting-sort stage 2: exclusive scan over 4M counts (2048 elems / block).
// ---------------------------------------------------------------------------
__global__ __launch_bounds__(256) void scan_local(const int* __restrict__ cnt,
                                                  int* __restrict__ off,
                                                  int* __restrict__ bsum) {
    __shared__ int ts[256];
    int b = blockIdx.x, t = threadIdx.x;
    int base = b * 2048 + t * 8;
    int v[8]; int s = 0;
#pragma unroll
    for (int i = 0; i < 8; ++i) {
        int idx = base + i;
        v[i] = (idx < P_C) ? cnt[idx] : 0;
        s += v[i];
    }
    ts[t] = s;
    __syncthreads();
    for (int ofs = 1; ofs < 256; ofs <<= 1) {
        int xv = (t >= ofs) ? ts[t - ofs] : 0;
        __syncthreads();
        ts[t] += xv;
        __syncthreads();
    }
    int run = ts[t] - s;
    if (t == 255) bsum[b] = ts[255];
#pragma unroll
    for (int i = 0; i < 8; ++i) {
        int idx = base + i;
        if (idx < P_C) off[idx] = run;
        run += v[i];
    }
}

__global__ void scan_top(int* __restrict__ bsum) {   // 1 block, 256 threads
    __shared__ int ts[256];
    int t = threadIdx.x;
    int base = t * 8;
    int v[8]; int s = 0;
#pragma unroll
    for (int i = 0; i < 8; ++i) {
        int idx = base + i;
        v[i] = (idx < NB1) ? bsum[idx] : 0;
        s += v[i];
    }
    ts[t] = s;
    __syncthreads();
    for (int ofs = 1; ofs < 256; ofs <<= 1) {
        int xv = (t >= ofs) ? ts[t - ofs] : 0;
        __syncthreads();
        ts[t] += xv;
        __syncthreads();
    }
    int run = ts[t] - s;
#pragma unroll
    for (int i = 0; i < 8; ++i) {
        int idx = base + i;
        if (idx < NB1) bsum[idx] = run;
        run += v[i];
    }
}

__global__ __launch_bounds__(256) void scan_add(int* __restrict__ off,
                                                const int* __restrict__ bsum,
                                                int* __restrict__ cur) {
    int b = blockIdx.x, t = threadIdx.x;
    int add = bsum[b];
    int base = b * 2048 + t * 8;
#pragma unroll
    for (int i = 0; i < 8; ++i) {
        int idx = base + i;
        if (idx < P_C) { int o = off[idx] + add; off[idx] = o; cur[idx] = o; }
    }
    if (b == 0 && t == 0) off[P_C] = 2 * P_C;
}

// ---------------------------------------------------------------------------
// counting-sort stage 3: scatter (col | src<<20, valbits) to sorted position.
// ---------------------------------------------------------------------------
__global__ __launch_bounds__(256) void scat(
        const int* __restrict__ r1, const int* __restrict__ c1, const float* __restrict__ v1,
        const int* __restrict__ r2, const int* __restrict__ c2, const float* __restrict__ v2,
        int* __restrict__ cur, uint2* __restrict__ suv) {
    int i = blockIdx.x * 256 + threadIdx.x;
    int row; unsigned key; float val;
    if (i < P_C)          { row = r1[i]; key = (unsigned)c1[i]; val = v1[i]; }
    else if (i < 2 * P_C) { int j = i - P_C; row = r2[j]; key = (unsigned)c2[j] | 0x100000u; val = v2[j]; }
    else return;
    int pos = atomicAdd(&cur[row], 1);
    suv[pos] = make_uint2(key, __float_as_uint(val));
}

// ---------------------------------------------------------------------------
// CSR gather: materialize nfeat chunk (no atomics, no memset), 2 slots/wave
// with interleaved independent load chains. Also fuses the degree scatter:
// slot positions {0,5,10,15} accumulate val*degs[col] over n2p entries.
// ---------------------------------------------------------------------------
__global__ __launch_bounds__(256) void gather_nfeat(
        const uint2* __restrict__ suv, const int* __restrict__ pOff,
        const float* __restrict__ x, const float* __restrict__ efeat,
        const float* __restrict__ degs,
        float* __restrict__ nfeatC, float* __restrict__ degD, int slot0) {
    int t = threadIdx.x;
    int d = t & 63;
    int p0 = slot0 + blockIdx.x * 8 + (t >> 6) * 2;   // wave-uniform
    int p1 = p0 + 1;
    int i0 = pOff[p0], e0 = pOff[p0 + 1];
    int i1 = pOff[p1], e1 = pOff[p1 + 1];
    float a0 = 0.f, a1 = 0.f, ds0 = 0.f, ds1 = 0.f;
    while (i0 < e0 || i1 < e1) {
        bool h0 = i0 < e0, h1 = i1 < e1;
        uint2 kv0, kv1;
        if (h0) kv0 = suv[i0];
        if (h1) kv1 = suv[i1];
        if (h0) {
            unsigned k = kv0.x; float v = __uint_as_float(kv0.y);
            const float* f = (k & 0x100000u) ? efeat : x;
            a0 = fmaf(v, f[(size_t)(k & 0xFFFFFu) * 64 + d], a0);
            if (!(k & 0x100000u)) ds0 = fmaf(v, degs[k & 0xFFFFFu], ds0);
            ++i0;
        }
        if (h1) {
            unsigned k = kv1.x; float v = __uint_as_float(kv1.y);
            const float* f = (k & 0x100000u) ? efeat : x;
            a1 = fmaf(v, f[(size_t)(k & 0xFFFFFu) * 64 + d], a1);
            if (!(k & 0x100000u)) ds1 = fmaf(v, degs[k & 0xFFFFFu], ds1);
            ++i1;
        }
    }
    nfeatC[(size_t)(p0 - slot0) * 64 + d] = a0;
    nfeatC[(size_t)(p1 - slot0) * 64 + d] = a1;
    if (d == 0) {
        int pos = p0 & 15;
        if (pos == 0 || pos == 5 || pos == 10 || pos == 15)
            degD[(size_t)(p0 >> 4) * 4 + pos / 5] = ds0;
        pos = p1 & 15;
        if (pos == 0 || pos == 5 || pos == 10 || pos == 15)
            degD[(size_t)(p1 >> 4) * 4 + pos / 5] = ds1;
    }
}

// ---------------------------------------------------------------------------
// degree-gate MLP over chunk rows [r0, r0+rows).
// ---------------------------------------------------------------------------
__global__ __launch_bounds__(256) void dg_gemm(
        const float* __restrict__ degD,
        const float* __restrict__ W0, const float* __restrict__ b0,
        const float* __restrict__ W1, const float* __restrict__ b1,
        float* __restrict__ dgb, int r0, int rows) {
    __shared__ float hidT[128][68];   // [h][r]
    __shared__ float w1T[128][68];    // [h][c]
    __shared__ float dloc[64][4];
    __shared__ float w0s[128][5];
    int t = threadIdx.x;
    int m0 = r0 + blockIdx.x * 64;
    int rend = r0 + rows;

    {
        int r = t >> 2, j = t & 3;
        int gr = m0 + r; if (gr >= rend) gr = rend - 1;
        dloc[r][j] = degD[(size_t)gr * 4 + j];
    }
    if (t < 128) {
        w0s[t][0] = W0[t * 4 + 0]; w0s[t][1] = W0[t * 4 + 1];
        w0s[t][2] = W0[t * 4 + 2]; w0s[t][3] = W0[t * 4 + 3];
        w0s[t][4] = b0[t];
    }
    for (int s = 0; s < 32; ++s) {
        int idx = t + s * 256;
        w1T[idx & 127][idx >> 7] = W1[idx];
    }
    __syncthreads();
    for (int s = 0; s < 32; ++s) {
        int idx = t + s * 256;
        int h = idx & 127, r = idx >> 7;
        float v = w0s[h][4] + dloc[r][0] * w0s[h][0] + dloc[r][1] * w0s[h][1]
                            + dloc[r][2] * w0s[h][2] + dloc[r][3] * w0s[h][3];
        hidT[h][r] = fmaxf(v, 0.f);
    }
    __syncthreads();

    int tm = t >> 4, tn = t & 15;
    float acc[4][4] = {};
#pragma unroll 8
    for (int k = 0; k < 128; ++k) {
        float4 a = *reinterpret_cast<const float4*>(&hidT[k][tm * 4]);
        float4 b = *reinterpret_cast<const float4*>(&w1T[k][tn * 4]);
        acc[0][0] = fmaf(a.x, b.x, acc[0][0]); acc[0][1] = fmaf(a.x, b.y, acc[0][1]);
        acc[0][2] = fmaf(a.x, b.z, acc[0][2]); acc[0][3] = fmaf(a.x, b.w, acc[0][3]);
        acc[1][0] = fmaf(a.y, b.x, acc[1][0]); acc[1][1] = fmaf(a.y, b.y, acc[1][1]);
        acc[1][2] = fmaf(a.y, b.z, acc[1][2]); acc[1][3] = fmaf(a.y, b.w, acc[1][3]);
        acc[2][0] = fmaf(a.z, b.x, acc[2][0]); acc[2][1] = fmaf(a.z, b.y, acc[2][1]);
        acc[2][2] = fmaf(a.z, b.z, acc[2][2]); acc[2][3] = fmaf(a.z, b.w, acc[2][3]);
        acc[3][0] = fmaf(a.w, b.x, acc[3][0]); acc[3][1] = fmaf(a.w, b.y, acc[3][1]);
        acc[3][2] = fmaf(a.w, b.z, acc[3][2]); acc[3][3] = fmaf(a.w, b.w, acc[3][3]);
    }
    float bb[4] = {b1[tn * 4 + 0], b1[tn * 4 + 1], b1[tn * 4 + 2], b1[tn * 4 + 3]};
#pragma unroll
    for (int i = 0; i < 4; ++i) {
        int grow = m0 + tm * 4 + i;
        if (grow < rend) {
            float4 o = {acc[i][0] + bb[0], acc[i][1] + bb[1],
                        acc[i][2] + bb[2], acc[i][3] + bb[3]};
            *reinterpret_cast<float4*>(&dgb[(size_t)grow * 64 + tn * 4]) = o;
        }
    }
}

// ---------------------------------------------------------------------------
// GEMM over materialized chunk: h = A[128x1024] @ Wr + bias ; relu ;
// h2 = h @ Wl^T + bl ; out = h2 * dg.  128 rows/block, 256 thr, acc 8x4.
// ---------------------------------------------------------------------------
__global__ __launch_bounds__(256) void gemm_chunk(
        const float* __restrict__ nfeatC, const float* __restrict__ WrT,
        const float* __restrict__ bias, const float* __restrict__ Wl,
        const float* __restrict__ bl, const float* __restrict__ dgb,
        float* __restrict__ outb, int r0, int rows) {
    __shared__ float As[128 * 68];   // [r][k], reused for H
    __shared__ float Bs[64 * 68];    // [c][k]
    int t = threadIdx.x;
    int m0 = blockIdx.x * 128;       // local row base within chunk
    int tm = t >> 4, tn = t & 15;
    float acc[8][4] = {};

    for (int l = 0; l < 16; ++l) {
        // stage W chunk: Bs[c][b] = WrT[(l*64+c)*64+b]
#pragma unroll
        for (int s = 0; s < 4; ++s) {
            int c = tm + s * 16;
            *reinterpret_cast<float4*>(&Bs[c * 68 + tn * 4]) =
                *reinterpret_cast<const float4*>(&WrT[(size_t)(l * 64 + c) * 64 + tn * 4]);
        }
        // stage A chunk: batched loads (8 outstanding) then LDS writes
        float4 va[8];
#pragma unroll
        for (int s = 0; s < 8; ++s) {
            int r = tm + s * 16;
            int lr = m0 + r; if (lr >= rows) lr = rows - 1;
            va[s] = *reinterpret_cast<const float4*>(
                &nfeatC[(size_t)lr * 1024 + l * 64 + tn * 4]);
        }
#pragma unroll
        for (int s = 0; s < 8; ++s) {
            int r = tm + s * 16;
            *reinterpret_cast<float4*>(&As[r * 68 + tn * 4]) = va[s];
        }
        __syncthreads();
#pragma unroll 4
        for (int k = 0; k < 64; k += 4) {
            float4 b0 = *reinterpret_cast<const float4*>(&Bs[(tn     ) * 68 + k]);
            float4 b1 = *reinterpret_cast<const float4*>(&Bs[(tn + 16) * 68 + k]);
            float4 b2 = *reinterpret_cast<const float4*>(&Bs[(tn + 32) * 68 + k]);
            float4 b3 = *reinterpret_cast<const float4*>(&Bs[(tn + 48) * 68 + k]);
#pragma unroll
            for (int i = 0; i < 8; ++i) {
                float4 a = *reinterpret_cast<const float4*>(&As[(tm + 16 * i) * 68 + k]);
                acc[i][0] = fmaf(a.w, b0.w, fmaf(a.z, b0.z, fmaf(a.y, b0.y, fmaf(a.x, b0.x, acc[i][0]))));
                acc[i][1] = fmaf(a.w, b1.w, fmaf(a.z, b1.z, fmaf(a.y, b1.y, fmaf(a.x, b1.x, acc[i][1]))));
                acc[i][2] = fmaf(a.w, b2.w, fmaf(a.z, b2.z, fmaf(a.y, b2.y, fmaf(a.x, b2.x, acc[i][2]))));
                acc[i][3] = fmaf(a.w, b3.w, fmaf(a.z, b3.z, fmaf(a.y, b3.y, fmaf(a.x, b3.x, acc[i][3]))));
            }
        }
        __syncthreads();
    }

    // epilogue 1: H = relu(h + bias) into As; stage Wl into Bs
    float bv[4];
#pragma unroll
    for (int j = 0; j < 4; ++j) bv[j] = bias[tn + 16 * j];
#pragma unroll
    for (int i = 0; i < 8; ++i)
#pragma unroll
        for (int j = 0; j < 4; ++j)
            As[(tm + 16 * i) * 68 + tn + 16 * j] = fmaxf(acc[i][j] + bv[j], 0.f);
#pragma unroll
    for (int s = 0; s < 4; ++s) {
        int c2 = tm + s * 16;
        *reinterpret_cast<float4*>(&Bs[c2 * 68 + tn * 4]) =
            *reinterpret_cast<const float4*>(&Wl[c2 * 64 + tn * 4]);
    }
    __syncthreads();

    float acc2[8][4] = {};
#pragma unroll 4
    for (int k = 0; k < 64; k += 4) {
        float4 b0 = *reinterpret_cast<const float4*>(&Bs[(tn     ) * 68 + k]);
        float4 b1 = *reinterpret_cast<const float4*>(&Bs[(tn + 16) * 68 + k]);
        float4 b2 = *reinterpret_cast<const float4*>(&Bs[(tn + 32) * 68 + k]);
        float4 b3 = *reinterpret_cast<const float4*>(&Bs[(tn + 48) * 68 + k]);
#pragma unroll
        for (int i = 0; i < 8; ++i) {
            float4 a = *reinterpret_cast<const float4*>(&As[(tm + 16 * i) * 68 + k]);
            acc2[i][0] = fmaf(a.w, b0.w, fmaf(a.z, b0.z, fmaf(a.y, b0.y, fmaf(a.x, b0.x, acc2[i][0]))));
            acc2[i][1] = fmaf(a.w, b1.w, fmaf(a.z, b1.z, fmaf(a.y, b1.y, fmaf(a.x, b1.x, acc2[i][1]))));
            acc2[i][2] = fmaf(a.w, b2.w, fmaf(a.z, b2.z, fmaf(a.y, b2.y, fmaf(a.x, b2.x, acc2[i][2]))));
            acc2[i][3] = fmaf(a.w, b3.w, fmaf(a.z, b3.z, fmaf(a.y, b3.y, fmaf(a.x, b3.x, acc2[i][3]))));
        }
    }
    float blv[4];
#pragma unroll
    for (int j = 0; j < 4; ++j) blv[j] = bl[tn + 16 * j];
#pragma unroll
    for (int i = 0; i < 8; ++i) {
        int lrow = m0 + tm + 16 * i;
        if (lrow < rows) {
            size_t grow = (size_t)(r0 + lrow);
#pragma unroll
            for (int j = 0; j < 4; ++j) {
                size_t idx = grow * 64 + tn + 16 * j;
                float g = dgb[idx];               // read before aliased write
                outb[idx] = (acc2[i][j] + blv[j]) * g;
            }
        }
    }
}

// ---------------------------------------------------------------------------
// pooling scatter, one wave per nnz.
// ---------------------------------------------------------------------------
__global__ __launch_bounds__(256) void pool_scatter(
        const int* __restrict__ prow, const int* __restrict__ pcol,
        const float* __restrict__ pval, const float* __restrict__ outb,
        float* __restrict__ out) {
    int t = blockIdx.x * 256 + threadIdx.x;
    int i = t >> 6, d = t & 63;
    if (i >= NPERM_C) return;
    int r = prow[i], c = pcol[i];
    float v = pval[i];
    atomicAdd(&out[(size_t)r * 64 + d], v * outb[(size_t)c * 64 + d]);
}

extern "C" void kernel_launch(void* const* d_in, const int* in_sizes, int n_in,
                              void* d_out, int out_size, void* d_ws, size_t ws_size,
                              hipStream_t stream) {
    const float* x       = (const float*)d_in[0];
    const float* efeat   = (const float*)d_in[1];
    const float* degs    = (const float*)d_in[2];
    const int*   n2p_row = (const int*)d_in[3];
    const int*   n2p_col = (const int*)d_in[4];
    const float* n2p_val = (const float*)d_in[5];
    const int*   e2p_row = (const int*)d_in[6];
    const int*   e2p_col = (const int*)d_in[7];
    const float* e2p_val = (const float*)d_in[8];
    const int*   pool_row = (const int*)d_in[9];
    const int*   pool_col = (const int*)d_in[10];
    const float* pool_val = (const float*)d_in[11];
    const float* weights = (const float*)d_in[12];
    const float* bias    = (const float*)d_in[13];
    const float* W0      = (const float*)d_in[14];
    const float* b0      = (const float*)d_in[15];
    const float* W1      = (const float*)d_in[16];
    const float* b1      = (const float*)d_in[17];
    const float* Wl      = (const float*)d_in[18];
    const float* bl      = (const float*)d_in[19];
    float* out = (float*)d_out;

    // workspace layout (4B elems):
    // suv[8M uint2 = 16M] | pOff[4M+64] | pCur/pCnt[4M] | bsum[2048]
    // | WrT[65536] | degD[1M] | dgb/outb[16M] | nfeatC[CH*1024]
    uint2* suv  = (uint2*)d_ws;
    int*   pOff = (int*)(suv + 8000000);
    int*   pCur = pOff + 4000064;          // doubles as pCnt
    int*   bsum = pCur + 4000000;
    float* WrT  = (float*)(bsum + 2048);
    float* degD = WrT + 65536;
    float* dgb  = degD + 1000000;
    float* outb = dgb;                     // alias (same-index read-then-write)
    float* nfeatC = dgb + 16000000;

    const long long base_elems = 16000000LL + 4000064 + 4000000 + 2048 +
                                 65536 + 1000000 + 16000000;   // 41,067,648
    long long availf = (long long)(ws_size / 4) - base_elems;
    long long chl = availf / 1024;
    if (chl > NPERM_C) chl = NPERM_C;
    int CH = (int)(chl & ~127LL);
    if (CH < 128) {   // cannot run: emit zeros cleanly instead of faulting
        hipMemsetAsync(d_out, 0, (size_t)out_size * 4, stream);
        return;
    }

    hipMemsetAsync(pCur, 0, (size_t)P_C * 4, stream);
    hipMemsetAsync(out, 0, (size_t)G_C * 64 * 4, stream);

    repack_w<<<256, 256, 0, stream>>>(weights, WrT);
    hist<<<31250, 256, 0, stream>>>(n2p_row, e2p_row, pCur);
    scan_local<<<NB1, 256, 0, stream>>>(pCur, pOff, bsum);
    scan_top<<<1, 256, 0, stream>>>(bsum);
    scan_add<<<NB1, 256, 0, stream>>>(pOff, bsum, pCur);
    scat<<<31250, 256, 0, stream>>>(n2p_row, n2p_col, n2p_val,
                                    e2p_row, e2p_col, e2p_val, pCur, suv);

    for (int c0 = 0; c0 < NPERM_C; c0 += CH) {
        int rows = NPERM_C - c0; if (rows > CH) rows = CH;
        gather_nfeat<<<rows * 2, 256, 0, stream>>>(
            suv, pOff, x, efeat, degs, nfeatC, degD, c0 * 16);
        dg_gemm<<<(rows + 63) / 64, 256, 0, stream>>>(
            degD, W0, b0, W1, b1, dgb, c0, rows);
        gemm_chunk<<<(rows + 127) / 128, 256, 0, stream>>>(
            nfeatC, WrT, bias, Wl, bl, dgb, outb, c0, rows);
    }

    pool_scatter<<<62500, 256, 0, stream>>>(pool_row, pool_col, pool_val, outb, out);
}

// Round 4
// 2755.953 us; speedup vs baseline: 1.4580x; 1.0860x over previous
//
#include <hip/hip_runtime.h>

#define NPERM_C 250000
#define P_C     4000000          // slots = NPERM * 16
#define G_C     4096
#define NB1     1954             // ceil(P_C / 2048) for the scan

typedef __attribute__((ext_vector_type(8))) short bf16x8;
typedef __attribute__((ext_vector_type(4))) float f32x4;

static __device__ __forceinline__ unsigned short f2bf(float f) {
    unsigned u = __float_as_uint(f);
    unsigned r = (u + 0x7fffu + ((u >> 16) & 1u)) >> 16;   // RNE
    return (unsigned short)r;
}
static __device__ __forceinline__ float bf2f(unsigned short s) {
    return __uint_as_float(((unsigned)s) << 16);
}

// ---------------------------------------------------------------------------
// Build fragment-ordered split-bf16 weight table for the einsum GEMM.
// o = ((((l*2+ks)*4+nt)*2+h)*64 + lane)*8 + j ; value = weights[(b*64+c)*16+l]
// with b = ks*32+(lane>>4)*8+j (K index), c = nt*16+(lane&15) (N index).
// ---------------------------------------------------------------------------
__global__ void repack_bpk(const float* __restrict__ w, unsigned short* __restrict__ bpk) {
    int o = blockIdx.x * 256 + threadIdx.x;          // 131072 total
    int j = o & 7, lane = (o >> 3) & 63, h = (o >> 9) & 1;
    int nt = (o >> 10) & 3, ks = (o >> 12) & 1, l = o >> 13;
    int b = ks * 32 + (lane >> 4) * 8 + j;
    int c = nt * 16 + (lane & 15);
    float wv = w[(b * 64 + c) * 16 + l];
    unsigned short hb = f2bf(wv);
    bpk[o] = (h == 0) ? hb : f2bf(wv - bf2f(hb));
}

// Same for Wl (h2 = h @ Wl^T): k = col of h, value = Wl[c2*64+k].
__global__ void repack_wlpk(const float* __restrict__ wl, unsigned short* __restrict__ wpk) {
    int o = blockIdx.x * 256 + threadIdx.x;          // 8192 total
    int j = o & 7, lane = (o >> 3) & 63, h = (o >> 9) & 1;
    int nt = (o >> 10) & 3, ks = o >> 12;
    int k = ks * 32 + (lane >> 4) * 8 + j;
    int c2 = nt * 16 + (lane & 15);
    float wv = wl[c2 * 64 + k];
    unsigned short hb = f2bf(wv);
    wpk[o] = (h == 0) ? hb : f2bf(wv - bf2f(hb));
}

// ---------------------------------------------------------------------------
// counting-sort stage 1: histogram of nnz per slot (both matrices).
// ---------------------------------------------------------------------------
__global__ __launch_bounds__(256) void hist(const int* __restrict__ r1,
                                            const int* __restrict__ r2,
                                            int* __restrict__ cnt) {
    int i = blockIdx.x * 256 + threadIdx.x;
    if (i < P_C)            atomicAdd(&cnt[r1[i]], 1);
    else if (i < 2 * P_C)   atomicAdd(&cnt[r2[i - P_C]], 1);
}

// ---------------------------------------------------------------------------
// counting-sort stage 2: exclusive scan over 4M counts (2048 elems / block).
// ---------------------------------------------------------------------------
__global__ __launch_bounds__(256) void scan_local(const int* __restrict__ cnt,
                                                  int* __restrict__ off,
                                                  int* __restrict__ bsum) {
    __shared__ int ts[256];
    int b = blockIdx.x, t = threadIdx.x;
    int base = b * 2048 + t * 8;
    int v[8]; int s = 0;
#pragma unroll
    for (int i = 0; i < 8; ++i) {
        int idx = base + i;
        v[i] = (idx < P_C) ? cnt[idx] : 0;
        s += v[i];
    }
    ts[t] = s;
    __syncthreads();
    for (int ofs = 1; ofs < 256; ofs <<= 1) {
        int xv = (t >= ofs) ? ts[t - ofs] : 0;
        __syncthreads();
        ts[t] += xv;
        __syncthreads();
    }
    int run = ts[t] - s;
    if (t == 255) bsum[b] = ts[255];
#pragma unroll
    for (int i = 0; i < 8; ++i) {
        int idx = base + i;
        if (idx < P_C) off[idx] = run;
        run += v[i];
    }
}

__global__ void scan_top(int* __restrict__ bsum) {   // 1 block, 256 threads
    __shared__ int ts[256];
    int t = threadIdx.x;
    int base = t * 8;
    int v[8]; int s = 0;
#pragma unroll
    for (int i = 0; i < 8; ++i) {
        int idx = base + i;
        v[i] = (idx < NB1) ? bsum[idx] : 0;
        s += v[i];
    }
    ts[t] = s;
    __syncthreads();
    for (int ofs = 1; ofs < 256; ofs <<= 1) {
        int xv = (t >= ofs) ? ts[t - ofs] : 0;
        __syncthreads();
        ts[t] += xv;
        __syncthreads();
    }
    int run = ts[t] - s;
#pragma unroll
    for (int i = 0; i < 8; ++i) {
        int idx = base + i;
        if (idx < NB1) bsum[idx] = run;
        run += v[i];
    }
}

__global__ __launch_bounds__(256) void scan_add(int* __restrict__ off,
                                                const int* __restrict__ bsum,
                                                int* __restrict__ cur) {
    int b = blockIdx.x, t = threadIdx.x;
    int add = bsum[b];
    int base = b * 2048 + t * 8;
#pragma unroll
    for (int i = 0; i < 8; ++i) {
        int idx = base + i;
        if (idx < P_C) { int o = off[idx] + add; off[idx] = o; cur[idx] = o; }
    }
    if (b == 0 && t == 0) off[P_C] = 2 * P_C;
}

// ---------------------------------------------------------------------------
// counting-sort stage 3: scatter (col | src<<20, valbits) to sorted position.
// ---------------------------------------------------------------------------
__global__ __launch_bounds__(256) void scat(
        const int* __restrict__ r1, const int* __restrict__ c1, const float* __restrict__ v1,
        const int* __restrict__ r2, const int* __restrict__ c2, const float* __restrict__ v2,
        int* __restrict__ cur, uint2* __restrict__ suv) {
    int i = blockIdx.x * 256 + threadIdx.x;
    int row; unsigned key; float val;
    if (i < P_C)          { row = r1[i]; key = (unsigned)c1[i]; val = v1[i]; }
    else if (i < 2 * P_C) { int j = i - P_C; row = r2[j]; key = (unsigned)c2[j] | 0x100000u; val = v2[j]; }
    else return;
    int pos = atomicAdd(&cur[row], 1);
    suv[pos] = make_uint2(key, __float_as_uint(val));
}

// ---------------------------------------------------------------------------
// CSR gather: materialize nfeat chunk as split-bf16 planes (hi, lo).
// 4 slots per wave, 4 interleaved independent load chains. Fuses the degree
// scatter (slot positions {0,5,10,15} accumulate val*degs[col], n2p only).
// ---------------------------------------------------------------------------
__global__ __launch_bounds__(256) void gather_nfeat(
        const uint2* __restrict__ suv, const int* __restrict__ pOff,
        const float* __restrict__ x, const float* __restrict__ efeat,
        const float* __restrict__ degs,
        unsigned short* __restrict__ nfH, unsigned short* __restrict__ nfL,
        float* __restrict__ degD, int slot0) {
    int t = threadIdx.x;
    int d = t & 63;
    int pb = slot0 + blockIdx.x * 16 + (t >> 6) * 4;   // wave-uniform
    int i0 = pOff[pb],     e0 = pOff[pb + 1];
    int i1 = pOff[pb + 1], e1 = pOff[pb + 2];
    int i2 = pOff[pb + 2], e2 = pOff[pb + 3];
    int i3 = pOff[pb + 3], e3 = pOff[pb + 4];
    float a0 = 0.f, a1 = 0.f, a2 = 0.f, a3 = 0.f;
    float s0 = 0.f, s1 = 0.f, s2 = 0.f, s3 = 0.f;
    while ((i0 < e0) | (i1 < e1) | (i2 < e2) | (i3 < e3)) {
        bool h0 = i0 < e0, h1 = i1 < e1, h2 = i2 < e2, h3 = i3 < e3;
        uint2 kv0, kv1, kv2, kv3;
        if (h0) kv0 = suv[i0];
        if (h1) kv1 = suv[i1];
        if (h2) kv2 = suv[i2];
        if (h3) kv3 = suv[i3];
        if (h0) {
            unsigned k = kv0.x; float v = __uint_as_float(kv0.y);
            const float* f = (k & 0x100000u) ? efeat : x;
            a0 = fmaf(v, f[(size_t)(k & 0xFFFFFu) * 64 + d], a0);
            if (!(k & 0x100000u)) s0 = fmaf(v, degs[k & 0xFFFFFu], s0);
            ++i0;
        }
        if (h1) {
            unsigned k = kv1.x; float v = __uint_as_float(kv1.y);
            const float* f = (k & 0x100000u) ? efeat : x;
            a1 = fmaf(v, f[(size_t)(k & 0xFFFFFu) * 64 + d], a1);
            if (!(k & 0x100000u)) s1 = fmaf(v, degs[k & 0xFFFFFu], s1);
            ++i1;
        }
        if (h2) {
            unsigned k = kv2.x; float v = __uint_as_float(kv2.y);
            const float* f = (k & 0x100000u) ? efeat : x;
            a2 = fmaf(v, f[(size_t)(k & 0xFFFFFu) * 64 + d], a2);
            if (!(k & 0x100000u)) s2 = fmaf(v, degs[k & 0xFFFFFu], s2);
            ++i2;
        }
        if (h3) {
            unsigned k = kv3.x; float v = __uint_as_float(kv3.y);
            const float* f = (k & 0x100000u) ? efeat : x;
            a3 = fmaf(v, f[(size_t)(k & 0xFFFFFu) * 64 + d], a3);
            if (!(k & 0x100000u)) s3 = fmaf(v, degs[k & 0xFFFFFu], s3);
            ++i3;
        }
    }
    float av[4] = {a0, a1, a2, a3};
    float sv[4] = {s0, s1, s2, s3};
#pragma unroll
    for (int c = 0; c < 4; ++c) {
        size_t o = (size_t)(pb + c - slot0) * 64 + d;
        unsigned short hb = f2bf(av[c]);
        nfH[o] = hb;
        nfL[o] = f2bf(av[c] - bf2f(hb));
        if (d == 0) {
            int pos = (pb + c) & 15;
            if (pos == 0 || pos == 5 || pos == 10 || pos == 15)
                degD[(size_t)((pb + c) >> 4) * 4 + pos / 5] = sv[c];
        }
    }
}

// ---------------------------------------------------------------------------
// degree-gate MLP over chunk rows [r0, r0+rows).
// ---------------------------------------------------------------------------
__global__ __launch_bounds__(256) void dg_gemm(
        const float* __restrict__ degD,
        const float* __restrict__ W0, const float* __restrict__ b0,
        const float* __restrict__ W1, const float* __restrict__ b1,
        float* __restrict__ dgb, int r0, int rows) {
    __shared__ float hidT[128][68];   // [h][r]
    __shared__ float w1T[128][68];    // [h][c]
    __shared__ float dloc[64][4];
    __shared__ float w0s[128][5];
    int t = threadIdx.x;
    int m0 = r0 + blockIdx.x * 64;
    int rend = r0 + rows;

    {
        int r = t >> 2, j = t & 3;
        int gr = m0 + r; if (gr >= rend) gr = rend - 1;
        dloc[r][j] = degD[(size_t)gr * 4 + j];
    }
    if (t < 128) {
        w0s[t][0] = W0[t * 4 + 0]; w0s[t][1] = W0[t * 4 + 1];
        w0s[t][2] = W0[t * 4 + 2]; w0s[t][3] = W0[t * 4 + 3];
        w0s[t][4] = b0[t];
    }
    for (int s = 0; s < 32; ++s) {
        int idx = t + s * 256;
        w1T[idx & 127][idx >> 7] = W1[idx];
    }
    __syncthreads();
    for (int s = 0; s < 32; ++s) {
        int idx = t + s * 256;
        int h = idx & 127, r = idx >> 7;
        float v = w0s[h][4] + dloc[r][0] * w0s[h][0] + dloc[r][1] * w0s[h][1]
                            + dloc[r][2] * w0s[h][2] + dloc[r][3] * w0s[h][3];
        hidT[h][r] = fmaxf(v, 0.f);
    }
    __syncthreads();

    int tm = t >> 4, tn = t & 15;
    float acc[4][4] = {};
#pragma unroll 8
    for (int k = 0; k < 128; ++k) {
        float4 a = *reinterpret_cast<const float4*>(&hidT[k][tm * 4]);
        float4 b = *reinterpret_cast<const float4*>(&w1T[k][tn * 4]);
        acc[0][0] = fmaf(a.x, b.x, acc[0][0]); acc[0][1] = fmaf(a.x, b.y, acc[0][1]);
        acc[0][2] = fmaf(a.x, b.z, acc[0][2]); acc[0][3] = fmaf(a.x, b.w, acc[0][3]);
        acc[1][0] = fmaf(a.y, b.x, acc[1][0]); acc[1][1] = fmaf(a.y, b.y, acc[1][1]);
        acc[1][2] = fmaf(a.y, b.z, acc[1][2]); acc[1][3] = fmaf(a.y, b.w, acc[1][3]);
        acc[2][0] = fmaf(a.z, b.x, acc[2][0]); acc[2][1] = fmaf(a.z, b.y, acc[2][1]);
        acc[2][2] = fmaf(a.z, b.z, acc[2][2]); acc[2][3] = fmaf(a.z, b.w, acc[2][3]);
        acc[3][0] = fmaf(a.w, b.x, acc[3][0]); acc[3][1] = fmaf(a.w, b.y, acc[3][1]);
        acc[3][2] = fmaf(a.w, b.z, acc[3][2]); acc[3][3] = fmaf(a.w, b.w, acc[3][3]);
    }
    float bb[4] = {b1[tn * 4 + 0], b1[tn * 4 + 1], b1[tn * 4 + 2], b1[tn * 4 + 3]};
#pragma unroll
    for (int i = 0; i < 4; ++i) {
        int grow = m0 + tm * 4 + i;
        if (grow < rend) {
            float4 o = {acc[i][0] + bb[0], acc[i][1] + bb[1],
                        acc[i][2] + bb[2], acc[i][3] + bb[3]};
            *reinterpret_cast<float4*>(&dgb[(size_t)grow * 64 + tn * 4]) = o;
        }
    }
}

// ---------------------------------------------------------------------------
// MFMA einsum + epilogue via split-bf16 (hi+lo; 3 products = fp32 accuracy).
// Block: 256 thr = 4 waves; wave owns 32 rows; tile 128x64, K=1024.
// A-frags straight from global (16B bf16x8), B-frags from fragment-ordered
// table (L2-resident). Second GEMM h@Wl^T via padded-LDS roundtrip + MFMA.
// ---------------------------------------------------------------------------
__global__ __launch_bounds__(256) void gemm_mfma(
        const unsigned short* __restrict__ nfH, const unsigned short* __restrict__ nfL,
        const unsigned short* __restrict__ Bpk, const unsigned short* __restrict__ Wlpk,
        const float* __restrict__ bias, const float* __restrict__ bl,
        const float* __restrict__ dgb, float* __restrict__ outb,
        int r0, int rows) {
    __shared__ unsigned short Hh[128][72];
    __shared__ unsigned short Hl[128][72];
    int t = threadIdx.x, lane = t & 63, w = t >> 6;
    int m0 = blockIdx.x * 128;
    int r16 = lane & 15, kg = lane >> 4;

    f32x4 acc[2][4];
#pragma unroll
    for (int i = 0; i < 2; ++i)
#pragma unroll
        for (int j = 0; j < 4; ++j) acc[i][j] = (f32x4){0.f, 0.f, 0.f, 0.f};

    for (int l = 0; l < 16; ++l) {
#pragma unroll
        for (int ks = 0; ks < 2; ++ks) {
            bf16x8 ah[2], al[2];
#pragma unroll
            for (int mt = 0; mt < 2; ++mt) {
                int lr = m0 + w * 32 + mt * 16 + r16;
                if (lr >= rows) lr = rows - 1;
                size_t off = ((size_t)lr * 16 + l) * 64 + ks * 32 + kg * 8;
                ah[mt] = *reinterpret_cast<const bf16x8*>(nfH + off);
                al[mt] = *reinterpret_cast<const bf16x8*>(nfL + off);
            }
#pragma unroll
            for (int nt = 0; nt < 4; ++nt) {
                const unsigned short* bb =
                    Bpk + (size_t)(((l * 2 + ks) * 4 + nt) * 2) * 512 + lane * 8;
                bf16x8 bh = *reinterpret_cast<const bf16x8*>(bb);
                bf16x8 blo = *reinterpret_cast<const bf16x8*>(bb + 512);
#pragma unroll
                for (int mt = 0; mt < 2; ++mt) {
                    acc[mt][nt] = __builtin_amdgcn_mfma_f32_16x16x32_bf16(ah[mt], bh,  acc[mt][nt], 0, 0, 0);
                    acc[mt][nt] = __builtin_amdgcn_mfma_f32_16x16x32_bf16(ah[mt], blo, acc[mt][nt], 0, 0, 0);
                    acc[mt][nt] = __builtin_amdgcn_mfma_f32_16x16x32_bf16(al[mt], bh,  acc[mt][nt], 0, 0, 0);
                }
            }
        }
    }

    // epilogue 1: h = relu(acc + bias) -> split-bf16 LDS planes
#pragma unroll
    for (int mt = 0; mt < 2; ++mt)
#pragma unroll
        for (int nt = 0; nt < 4; ++nt) {
            int col = nt * 16 + r16;
            float bv = bias[col];
#pragma unroll
            for (int reg = 0; reg < 4; ++reg) {
                int rl = w * 32 + mt * 16 + kg * 4 + reg;
                float h = fmaxf(acc[mt][nt][reg] + bv, 0.f);
                unsigned short hb = f2bf(h);
                Hh[rl][col] = hb;
                Hl[rl][col] = f2bf(h - bf2f(hb));
            }
        }
    __syncthreads();

    f32x4 acc2[2][4];
#pragma unroll
    for (int i = 0; i < 2; ++i)
#pragma unroll
        for (int j = 0; j < 4; ++j) acc2[i][j] = (f32x4){0.f, 0.f, 0.f, 0.f};

#pragma unroll
    for (int ks = 0; ks < 2; ++ks) {
        bf16x8 ah[2], al[2];
#pragma unroll
        for (int mt = 0; mt < 2; ++mt) {
            int rl = w * 32 + mt * 16 + r16;
            ah[mt] = *reinterpret_cast<const bf16x8*>(&Hh[rl][ks * 32 + kg * 8]);
            al[mt] = *reinterpret_cast<const bf16x8*>(&Hl[rl][ks * 32 + kg * 8]);
        }
#pragma unroll
        for (int nt = 0; nt < 4; ++nt) {
            const unsigned short* wb =
                Wlpk + (size_t)(((ks * 4 + nt) * 2)) * 512 + lane * 8;
            bf16x8 bh = *reinterpret_cast<const bf16x8*>(wb);
            bf16x8 blo = *reinterpret_cast<const bf16x8*>(wb + 512);
#pragma unroll
            for (int mt = 0; mt < 2; ++mt) {
                acc2[mt][nt] = __builtin_amdgcn_mfma_f32_16x16x32_bf16(ah[mt], bh,  acc2[mt][nt], 0, 0, 0);
                acc2[mt][nt] = __builtin_amdgcn_mfma_f32_16x16x32_bf16(ah[mt], blo, acc2[mt][nt], 0, 0, 0);
                acc2[mt][nt] = __builtin_amdgcn_mfma_f32_16x16x32_bf16(al[mt], bh,  acc2[mt][nt], 0, 0, 0);
            }
        }
    }

    // epilogue 2: out = (h2 + bl) * dg
#pragma unroll
    for (int mt = 0; mt < 2; ++mt)
#pragma unroll
        for (int nt = 0; nt < 4; ++nt) {
            int col = nt * 16 + r16;
            float bv = bl[col];
#pragma unroll
            for (int reg = 0; reg < 4; ++reg) {
                int rl = w * 32 + mt * 16 + kg * 4 + reg;
                if (m0 + rl < rows) {
                    size_t idx = (size_t)(r0 + m0 + rl) * 64 + col;
                    outb[idx] = (acc2[mt][nt][reg] + bv) * dgb[idx];
                }
            }
        }
}

// ---------------------------------------------------------------------------
// pooling scatter, one wave per nnz.
// ---------------------------------------------------------------------------
__global__ __launch_bounds__(256) void pool_scatter(
        const int* __restrict__ prow, const int* __restrict__ pcol,
        const float* __restrict__ pval, const float* __restrict__ outb,
        float* __restrict__ out) {
    int t = blockIdx.x * 256 + threadIdx.x;
    int i = t >> 6, d = t & 63;
    if (i >= NPERM_C) return;
    int r = prow[i], c = pcol[i];
    float v = pval[i];
    atomicAdd(&out[(size_t)r * 64 + d], v * outb[(size_t)c * 64 + d]);
}

extern "C" void kernel_launch(void* const* d_in, const int* in_sizes, int n_in,
                              void* d_out, int out_size, void* d_ws, size_t ws_size,
                              hipStream_t stream) {
    const float* x       = (const float*)d_in[0];
    const float* efeat   = (const float*)d_in[1];
    const float* degs    = (const float*)d_in[2];
    const int*   n2p_row = (const int*)d_in[3];
    const int*   n2p_col = (const int*)d_in[4];
    const float* n2p_val = (const float*)d_in[5];
    const int*   e2p_row = (const int*)d_in[6];
    const int*   e2p_col = (const int*)d_in[7];
    const float* e2p_val = (const float*)d_in[8];
    const int*   pool_row = (const int*)d_in[9];
    const int*   pool_col = (const int*)d_in[10];
    const float* pool_val = (const float*)d_in[11];
    const float* weights = (const float*)d_in[12];
    const float* bias    = (const float*)d_in[13];
    const float* W0      = (const float*)d_in[14];
    const float* b0      = (const float*)d_in[15];
    const float* W1      = (const float*)d_in[16];
    const float* b1      = (const float*)d_in[17];
    const float* Wl      = (const float*)d_in[18];
    const float* bl      = (const float*)d_in[19];
    float* out = (float*)d_out;

    // workspace layout (4B elems):
    // suv[8M uint2=16M] | pOff[4M+64] | pCur[4M] | bsum[2048] | Bpk[64K]
    // | Wlpk[4K] | degD[1M] | dgb/outb[16M] | nfH+nfL[CH*1024]
    uint2* suv  = (uint2*)d_ws;
    int*   pOff = (int*)(suv + 8000000);
    int*   pCur = pOff + 4000064;
    int*   bsum = pCur + 4000000;
    unsigned short* Bpk  = (unsigned short*)(bsum + 2048);   // 131072 ushort
    unsigned short* Wlpk = Bpk + 131072;                     //   8192 ushort
    float* degD = (float*)(Wlpk + 8192);
    float* dgb  = degD + 1000000;
    float* outb = dgb;                     // alias (same-index read-then-write)
    unsigned short* nfH = (unsigned short*)(dgb + 16000000);

    const long long base_elems = 16000000LL + 4000064 + 4000000 + 2048 +
                                 65536 + 4096 + 1000000 + 16000000;
    long long availf = (long long)(ws_size / 4) - base_elems;
    long long chl = availf / 1024;         // per row: 2 planes * 16*64*2B
    if (chl > NPERM_C) chl = NPERM_C;
    int CH = (int)(chl & ~127LL);
    if (CH < 128) {   // cannot run: emit zeros cleanly instead of faulting
        hipMemsetAsync(d_out, 0, (size_t)out_size * 4, stream);
        return;
    }
    unsigned short* nfL = nfH + (size_t)CH * 1024;

    hipMemsetAsync(pCur, 0, (size_t)P_C * 4, stream);
    hipMemsetAsync(out, 0, (size_t)G_C * 64 * 4, stream);

    repack_bpk<<<512, 256, 0, stream>>>(weights, Bpk);
    repack_wlpk<<<32, 256, 0, stream>>>(Wl, Wlpk);
    hist<<<31250, 256, 0, stream>>>(n2p_row, e2p_row, pCur);
    scan_local<<<NB1, 256, 0, stream>>>(pCur, pOff, bsum);
    scan_top<<<1, 256, 0, stream>>>(bsum);
    scan_add<<<NB1, 256, 0, stream>>>(pOff, bsum, pCur);
    scat<<<31250, 256, 0, stream>>>(n2p_row, n2p_col, n2p_val,
                                    e2p_row, e2p_col, e2p_val, pCur, suv);

    for (int c0 = 0; c0 < NPERM_C; c0 += CH) {
        int rows = NPERM_C - c0; if (rows > CH) rows = CH;
        gather_nfeat<<<rows, 256, 0, stream>>>(
            suv, pOff, x, efeat, degs, nfH, nfL, degD, c0 * 16);
        dg_gemm<<<(rows + 63) / 64, 256, 0, stream>>>(
            degD, W0, b0, W1, b1, dgb, c0, rows);
        gemm_mfma<<<(rows + 127) / 128, 256, 0, stream>>>(
            nfH, nfL, Bpk, Wlpk, bias, bl, dgb, outb, c0, rows);
    }

    pool_scatter<<<62500, 256, 0, stream>>>(pool_row, pool_col, pool_val, outb, out);
}

// Round 5
// 1494.173 us; speedup vs baseline: 2.6892x; 1.8445x over previous
//
#include <hip/hip_runtime.h>

#define NPERM_C 250000
#define P_C     4000000          // slots = NPERM * 16
#define G_C     4096
#define NB1     1954             // ceil(P_C / 2048) big scan
#define NB2     123              // ceil(NPERM_C / 2048) pool scan

typedef __attribute__((ext_vector_type(8))) short bf16x8;
typedef __attribute__((ext_vector_type(4))) float f32x4;

static __device__ __forceinline__ unsigned short f2bf(float f) {
    unsigned u = __float_as_uint(f);
    unsigned r = (u + 0x7fffu + ((u >> 16) & 1u)) >> 16;   // RNE
    return (unsigned short)r;
}
static __device__ __forceinline__ float bf2f(unsigned short s) {
    return __uint_as_float(((unsigned)s) << 16);
}

// ---------------------------------------------------------------------------
// fragment-ordered split-bf16 weight tables (unchanged from round 4)
// ---------------------------------------------------------------------------
__global__ void repack_bpk(const float* __restrict__ w, unsigned short* __restrict__ bpk) {
    int o = blockIdx.x * 256 + threadIdx.x;          // 131072 total
    int j = o & 7, lane = (o >> 3) & 63, h = (o >> 9) & 1;
    int nt = (o >> 10) & 3, ks = (o >> 12) & 1, l = o >> 13;
    int b = ks * 32 + (lane >> 4) * 8 + j;
    int c = nt * 16 + (lane & 15);
    float wv = w[(b * 64 + c) * 16 + l];
    unsigned short hb = f2bf(wv);
    bpk[o] = (h == 0) ? hb : f2bf(wv - bf2f(hb));
}

__global__ void repack_wlpk(const float* __restrict__ wl, unsigned short* __restrict__ wpk) {
    int o = blockIdx.x * 256 + threadIdx.x;          // 8192 total
    int j = o & 7, lane = (o >> 3) & 63, h = (o >> 9) & 1;
    int nt = (o >> 10) & 3, ks = o >> 12;
    int k = ks * 32 + (lane >> 4) * 8 + j;
    int c2 = nt * 16 + (lane & 15);
    float wv = wl[c2 * 64 + k];
    unsigned short hb = f2bf(wv);
    wpk[o] = (h == 0) ? hb : f2bf(wv - bf2f(hb));
}

// ---------------------------------------------------------------------------
// pool reference histogram: poolCnt[c] = #times perm row c is pooled.
// ---------------------------------------------------------------------------
__global__ __launch_bounds__(256) void pool_hist(const int* __restrict__ pcol,
                                                 int* __restrict__ poolCnt) {
    int i = blockIdx.x * 256 + threadIdx.x;
    if (i < NPERM_C) atomicAdd(&poolCnt[pcol[i]], 1);
}

// active-row compaction scan (flag = cnt!=0), deterministic.
__global__ __launch_bounds__(256) void pool_scan_local(const int* __restrict__ poolCnt,
                                                       int* __restrict__ poolRank,
                                                       int* __restrict__ bsum2) {
    __shared__ int ts[256];
    int b = blockIdx.x, t = threadIdx.x;
    int base = b * 2048 + t * 8;
    int v[8]; int s = 0;
#pragma unroll
    for (int i = 0; i < 8; ++i) {
        int idx = base + i;
        v[i] = (idx < NPERM_C) ? (poolCnt[idx] != 0) : 0;
        s += v[i];
    }
    ts[t] = s;
    __syncthreads();
    for (int ofs = 1; ofs < 256; ofs <<= 1) {
        int xv = (t >= ofs) ? ts[t - ofs] : 0;
        __syncthreads();
        ts[t] += xv;
        __syncthreads();
    }
    int run = ts[t] - s;
    if (t == 255) bsum2[b] = ts[255];
#pragma unroll
    for (int i = 0; i < 8; ++i) {
        int idx = base + i;
        if (idx < NPERM_C) poolRank[idx] = run;
        run += v[i];
    }
}

__global__ void pool_scan_top(int* __restrict__ bsum2) {
    __shared__ int ts[256];
    int t = threadIdx.x;
    int v = (t < NB2) ? bsum2[t] : 0;
    ts[t] = v;
    __syncthreads();
    for (int ofs = 1; ofs < 256; ofs <<= 1) {
        int xv = (t >= ofs) ? ts[t - ofs] : 0;
        __syncthreads();
        ts[t] += xv;
        __syncthreads();
    }
    if (t < NB2) bsum2[t] = ts[t] - v;
}

__global__ __launch_bounds__(256) void pool_scan_add(const int* __restrict__ poolCnt,
                                                     int* __restrict__ poolRank,
                                                     const int* __restrict__ bsum2,
                                                     int* __restrict__ act,
                                                     int* __restrict__ nActB) {
    int b = blockIdx.x, t = threadIdx.x;
    int add = bsum2[b];
    int base = b * 2048 + t * 8;
#pragma unroll
    for (int i = 0; i < 8; ++i) {
        int idx = base + i;
        if (idx < NPERM_C) {
            int flag = poolCnt[idx] != 0;
            int o = poolRank[idx] + add;
            poolRank[idx] = o;
            if (flag) act[o] = idx;
            if (idx == NPERM_C - 1) nActB[0] = o + flag;
        }
    }
}

// ---------------------------------------------------------------------------
// slot histogram over ACTIVE rows only.
// ---------------------------------------------------------------------------
__global__ __launch_bounds__(256) void hist(const int* __restrict__ r1,
                                            const int* __restrict__ r2,
                                            const int* __restrict__ poolCnt,
                                            int* __restrict__ cnt) {
    int i = blockIdx.x * 256 + threadIdx.x;
    int r;
    if (i < P_C)            r = r1[i];
    else if (i < 2 * P_C)   r = r2[i - P_C];
    else return;
    if (poolCnt[r >> 4] != 0) atomicAdd(&cnt[r], 1);
}

// big exclusive scan over 4M slot counts.
__global__ __launch_bounds__(256) void scan_local(const int* __restrict__ cnt,
                                                  int* __restrict__ off,
                                                  int* __restrict__ bsum) {
    __shared__ int ts[256];
    int b = blockIdx.x, t = threadIdx.x;
    int base = b * 2048 + t * 8;
    int v[8]; int s = 0;
#pragma unroll
    for (int i = 0; i < 8; ++i) {
        int idx = base + i;
        v[i] = (idx < P_C) ? cnt[idx] : 0;
        s += v[i];
    }
    ts[t] = s;
    __syncthreads();
    for (int ofs = 1; ofs < 256; ofs <<= 1) {
        int xv = (t >= ofs) ? ts[t - ofs] : 0;
        __syncthreads();
        ts[t] += xv;
        __syncthreads();
    }
    int run = ts[t] - s;
    if (t == 255) bsum[b] = ts[255];
#pragma unroll
    for (int i = 0; i < 8; ++i) {
        int idx = base + i;
        if (idx < P_C) off[idx] = run;
        run += v[i];
    }
}

__global__ void scan_top(int* __restrict__ bsum) {
    __shared__ int ts[256];
    int t = threadIdx.x;
    int base = t * 8;
    int v[8]; int s = 0;
#pragma unroll
    for (int i = 0; i < 8; ++i) {
        int idx = base + i;
        v[i] = (idx < NB1) ? bsum[idx] : 0;
        s += v[i];
    }
    ts[t] = s;
    __syncthreads();
    for (int ofs = 1; ofs < 256; ofs <<= 1) {
        int xv = (t >= ofs) ? ts[t - ofs] : 0;
        __syncthreads();
        ts[t] += xv;
        __syncthreads();
    }
    int run = ts[t] - s;
#pragma unroll
    for (int i = 0; i < 8; ++i) {
        int idx = base + i;
        if (idx < NB1) bsum[idx] = run;
        run += v[i];
    }
}

__global__ __launch_bounds__(256) void scan_add(int* __restrict__ off,
                                                const int* __restrict__ bsum,
                                                int* __restrict__ cur) {
    int b = blockIdx.x, t = threadIdx.x;
    int add = bsum[b];
    int base = b * 2048 + t * 8;
#pragma unroll
    for (int i = 0; i < 8; ++i) {
        int idx = base + i;
        if (idx < P_C) {
            int o = off[idx] + add;
            if (idx == P_C - 1) off[P_C] = o + cur[idx];  // cur still holds count
            off[idx] = o;
            cur[idx] = o;
        }
    }
}

// ---------------------------------------------------------------------------
// scatter active entries to sorted position.
// ---------------------------------------------------------------------------
__global__ __launch_bounds__(256) void scat(
        const int* __restrict__ r1, const int* __restrict__ c1, const float* __restrict__ v1,
        const int* __restrict__ r2, const int* __restrict__ c2, const float* __restrict__ v2,
        const int* __restrict__ poolCnt,
        int* __restrict__ cur, uint2* __restrict__ suv) {
    int i = blockIdx.x * 256 + threadIdx.x;
    int row; unsigned key; float val;
    if (i < P_C)          { row = r1[i]; key = (unsigned)c1[i]; val = v1[i]; }
    else if (i < 2 * P_C) { int j = i - P_C; row = r2[j]; key = (unsigned)c2[j] | 0x100000u; val = v2[j]; }
    else return;
    if (poolCnt[row >> 4] == 0) return;
    int pos = atomicAdd(&cur[row], 1);
    suv[pos] = make_uint2(key, __float_as_uint(val));
}

// ---------------------------------------------------------------------------
// CSR gather, float4-per-lane: 16-lane group owns 2 chains; wave = 8 slots;
// block = 2 compact rows. Writes split-bf16 planes + all 4 degree-gate slots.
// ---------------------------------------------------------------------------
__global__ __launch_bounds__(256) void gather_nfeat(
        const uint2* __restrict__ suv, const int* __restrict__ pOff,
        const float* __restrict__ x, const float* __restrict__ efeat,
        const float* __restrict__ degs, const int* __restrict__ act,
        const int* __restrict__ nActB,
        unsigned short* __restrict__ nfH, unsigned short* __restrict__ nfL,
        float* __restrict__ degD, int row0, int rows) {
    int nAct = nActB[0];
    int t = threadIdx.x;
    int w = t >> 6, lane = t & 63;
    int g = lane >> 4, t16 = lane & 15;
    int cr = row0 + blockIdx.x * 2 + (w >> 1);
    int rend = row0 + rows; if (rend > nAct) rend = nAct;
    if (cr >= rend) return;                 // wave-uniform
    int arow = act[cr];
    int posA = (w & 1) * 8 + g * 2;
    int posB = posA + 1;
    int sA = arow * 16 + posA;
    int iA = pOff[sA];
    int eA = pOff[sA + 1];
    int iB = eA;
    int eB = pOff[sA + 2];
    bool needA = (posA == 0) || (posA == 10);
    bool needB = (posB == 5) || (posB == 15);
    float4 aA = {0.f, 0.f, 0.f, 0.f}, aB = {0.f, 0.f, 0.f, 0.f};
    float dA = 0.f, dB = 0.f;
    while ((iA < eA) || (iB < eB)) {
        bool hA = iA < eA, hB = iB < eB;
        uint2 kvA, kvB;
        if (hA) kvA = suv[iA];
        if (hB) kvB = suv[iB];
        if (hA) {
            unsigned k = kvA.x; float v = __uint_as_float(kvA.y);
            const float* f = (k & 0x100000u) ? efeat : x;
            float4 fv = *reinterpret_cast<const float4*>(
                f + (size_t)(k & 0xFFFFFu) * 64 + t16 * 4);
            aA.x = fmaf(v, fv.x, aA.x); aA.y = fmaf(v, fv.y, aA.y);
            aA.z = fmaf(v, fv.z, aA.z); aA.w = fmaf(v, fv.w, aA.w);
            if (needA && !(k & 0x100000u)) dA = fmaf(v, degs[k & 0xFFFFFu], dA);
            ++iA;
        }
        if (hB) {
            unsigned k = kvB.x; float v = __uint_as_float(kvB.y);
            const float* f = (k & 0x100000u) ? efeat : x;
            float4 fv = *reinterpret_cast<const float4*>(
                f + (size_t)(k & 0xFFFFFu) * 64 + t16 * 4);
            aB.x = fmaf(v, fv.x, aB.x); aB.y = fmaf(v, fv.y, aB.y);
            aB.z = fmaf(v, fv.z, aB.z); aB.w = fmaf(v, fv.w, aB.w);
            if (needB && !(k & 0x100000u)) dB = fmaf(v, degs[k & 0xFFFFFu], dB);
            ++iB;
        }
    }
    size_t o = ((size_t)(cr - row0) * 16 + posA) * 64 + t16 * 4;
    ushort4 h4, l4;
    h4.x = f2bf(aA.x); l4.x = f2bf(aA.x - bf2f(h4.x));
    h4.y = f2bf(aA.y); l4.y = f2bf(aA.y - bf2f(h4.y));
    h4.z = f2bf(aA.z); l4.z = f2bf(aA.z - bf2f(h4.z));
    h4.w = f2bf(aA.w); l4.w = f2bf(aA.w - bf2f(h4.w));
    *reinterpret_cast<ushort4*>(nfH + o) = h4;
    *reinterpret_cast<ushort4*>(nfL + o) = l4;
    h4.x = f2bf(aB.x); l4.x = f2bf(aB.x - bf2f(h4.x));
    h4.y = f2bf(aB.y); l4.y = f2bf(aB.y - bf2f(h4.y));
    h4.z = f2bf(aB.z); l4.z = f2bf(aB.z - bf2f(h4.z));
    h4.w = f2bf(aB.w); l4.w = f2bf(aB.w - bf2f(h4.w));
    *reinterpret_cast<ushort4*>(nfH + o + 64) = h4;
    *reinterpret_cast<ushort4*>(nfL + o + 64) = l4;
    if (t16 == 0) {
        if (needA) degD[(size_t)cr * 4 + posA / 5] = dA;
        if (needB) degD[(size_t)cr * 4 + posB / 5] = dB;
    }
}

// ---------------------------------------------------------------------------
// degree-gate MLP over compact rows [r0, min(r0+rows, nAct)).
// ---------------------------------------------------------------------------
__global__ __launch_bounds__(256) void dg_gemm(
        const float* __restrict__ degD,
        const float* __restrict__ W0, const float* __restrict__ b0,
        const float* __restrict__ W1, const float* __restrict__ b1,
        const int* __restrict__ nActB,
        float* __restrict__ dgb, int r0, int rows) {
    __shared__ float hidT[128][68];   // [h][r]
    __shared__ float w1T[128][68];    // [h][c]
    __shared__ float dloc[64][4];
    __shared__ float w0s[128][5];
    int nAct = nActB[0];
    int rend = r0 + rows; if (rend > nAct) rend = nAct;
    int t = threadIdx.x;
    int m0 = r0 + blockIdx.x * 64;
    if (m0 >= rend) return;

    {
        int r = t >> 2, j = t & 3;
        int gr = m0 + r; if (gr >= rend) gr = rend - 1;
        dloc[r][j] = degD[(size_t)gr * 4 + j];
    }
    if (t < 128) {
        w0s[t][0] = W0[t * 4 + 0]; w0s[t][1] = W0[t * 4 + 1];
        w0s[t][2] = W0[t * 4 + 2]; w0s[t][3] = W0[t * 4 + 3];
        w0s[t][4] = b0[t];
    }
    for (int s = 0; s < 32; ++s) {
        int idx = t + s * 256;
        w1T[idx & 127][idx >> 7] = W1[idx];
    }
    __syncthreads();
    for (int s = 0; s < 32; ++s) {
        int idx = t + s * 256;
        int h = idx & 127, r = idx >> 7;
        float v = w0s[h][4] + dloc[r][0] * w0s[h][0] + dloc[r][1] * w0s[h][1]
                            + dloc[r][2] * w0s[h][2] + dloc[r][3] * w0s[h][3];
        hidT[h][r] = fmaxf(v, 0.f);
    }
    __syncthreads();

    int tm = t >> 4, tn = t & 15;
    float acc[4][4] = {};
#pragma unroll 8
    for (int k = 0; k < 128; ++k) {
        float4 a = *reinterpret_cast<const float4*>(&hidT[k][tm * 4]);
        float4 b = *reinterpret_cast<const float4*>(&w1T[k][tn * 4]);
        acc[0][0] = fmaf(a.x, b.x, acc[0][0]); acc[0][1] = fmaf(a.x, b.y, acc[0][1]);
        acc[0][2] = fmaf(a.x, b.z, acc[0][2]); acc[0][3] = fmaf(a.x, b.w, acc[0][3]);
        acc[1][0] = fmaf(a.y, b.x, acc[1][0]); acc[1][1] = fmaf(a.y, b.y, acc[1][1]);
        acc[1][2] = fmaf(a.y, b.z, acc[1][2]); acc[1][3] = fmaf(a.y, b.w, acc[1][3]);
        acc[2][0] = fmaf(a.z, b.x, acc[2][0]); acc[2][1] = fmaf(a.z, b.y, acc[2][1]);
        acc[2][2] = fmaf(a.z, b.z, acc[2][2]); acc[2][3] = fmaf(a.z, b.w, acc[2][3]);
        acc[3][0] = fmaf(a.w, b.x, acc[3][0]); acc[3][1] = fmaf(a.w, b.y, acc[3][1]);
        acc[3][2] = fmaf(a.w, b.z, acc[3][2]); acc[3][3] = fmaf(a.w, b.w, acc[3][3]);
    }
    float bb[4] = {b1[tn * 4 + 0], b1[tn * 4 + 1], b1[tn * 4 + 2], b1[tn * 4 + 3]};
#pragma unroll
    for (int i = 0; i < 4; ++i) {
        int grow = m0 + tm * 4 + i;
        if (grow < rend) {
            float4 o = {acc[i][0] + bb[0], acc[i][1] + bb[1],
                        acc[i][2] + bb[2], acc[i][3] + bb[3]};
            *reinterpret_cast<float4*>(&dgb[(size_t)grow * 64 + tn * 4]) = o;
        }
    }
}

// ---------------------------------------------------------------------------
// MFMA einsum + epilogue (split-bf16, 3 products) over compact rows.
// ---------------------------------------------------------------------------
__global__ __launch_bounds__(256) void gemm_mfma(
        const unsigned short* __restrict__ nfH, const unsigned short* __restrict__ nfL,
        const unsigned short* __restrict__ Bpk, const unsigned short* __restrict__ Wlpk,
        const float* __restrict__ bias, const float* __restrict__ bl,
        const float* __restrict__ dgb, const int* __restrict__ nActB,
        float* __restrict__ outb, int r0, int rows) {
    __shared__ unsigned short Hh[128][72];
    __shared__ unsigned short Hl[128][72];
    int nAct = nActB[0];
    int rowsEff = rows; if (r0 + rowsEff > nAct) rowsEff = nAct - r0;
    int t = threadIdx.x, lane = t & 63, w = t >> 6;
    int m0 = blockIdx.x * 128;
    if (m0 >= rowsEff) return;
    int r16 = lane & 15, kg = lane >> 4;

    f32x4 acc[2][4];
#pragma unroll
    for (int i = 0; i < 2; ++i)
#pragma unroll
        for (int j = 0; j < 4; ++j) acc[i][j] = (f32x4){0.f, 0.f, 0.f, 0.f};

    for (int l = 0; l < 16; ++l) {
#pragma unroll
        for (int ks = 0; ks < 2; ++ks) {
            bf16x8 ah[2], al[2];
#pragma unroll
            for (int mt = 0; mt < 2; ++mt) {
                int lr = m0 + w * 32 + mt * 16 + r16;
                if (lr >= rowsEff) lr = rowsEff - 1;
                size_t off = ((size_t)lr * 16 + l) * 64 + ks * 32 + kg * 8;
                ah[mt] = *reinterpret_cast<const bf16x8*>(nfH + off);
                al[mt] = *reinterpret_cast<const bf16x8*>(nfL + off);
            }
#pragma unroll
            for (int nt = 0; nt < 4; ++nt) {
                const unsigned short* bb =
                    Bpk + (size_t)(((l * 2 + ks) * 4 + nt) * 2) * 512 + lane * 8;
                bf16x8 bh = *reinterpret_cast<const bf16x8*>(bb);
                bf16x8 blo = *reinterpret_cast<const bf16x8*>(bb + 512);
#pragma unroll
                for (int mt = 0; mt < 2; ++mt) {
                    acc[mt][nt] = __builtin_amdgcn_mfma_f32_16x16x32_bf16(ah[mt], bh,  acc[mt][nt], 0, 0, 0);
                    acc[mt][nt] = __builtin_amdgcn_mfma_f32_16x16x32_bf16(ah[mt], blo, acc[mt][nt], 0, 0, 0);
                    acc[mt][nt] = __builtin_amdgcn_mfma_f32_16x16x32_bf16(al[mt], bh,  acc[mt][nt], 0, 0, 0);
                }
            }
        }
    }

    // epilogue 1: h = relu(acc + bias) -> split-bf16 LDS planes
#pragma unroll
    for (int mt = 0; mt < 2; ++mt)
#pragma unroll
        for (int nt = 0; nt < 4; ++nt) {
            int col = nt * 16 + r16;
            float bv = bias[col];
#pragma unroll
            for (int reg = 0; reg < 4; ++reg) {
                int rl = w * 32 + mt * 16 + kg * 4 + reg;
                float h = fmaxf(acc[mt][nt][reg] + bv, 0.f);
                unsigned short hb = f2bf(h);
                Hh[rl][col] = hb;
                Hl[rl][col] = f2bf(h - bf2f(hb));
            }
        }
    __syncthreads();

    f32x4 acc2[2][4];
#pragma unroll
    for (int i = 0; i < 2; ++i)
#pragma unroll
        for (int j = 0; j < 4; ++j) acc2[i][j] = (f32x4){0.f, 0.f, 0.f, 0.f};

#pragma unroll
    for (int ks = 0; ks < 2; ++ks) {
        bf16x8 ah[2], al[2];
#pragma unroll
        for (int mt = 0; mt < 2; ++mt) {
            int rl = w * 32 + mt * 16 + r16;
            ah[mt] = *reinterpret_cast<const bf16x8*>(&Hh[rl][ks * 32 + kg * 8]);
            al[mt] = *reinterpret_cast<const bf16x8*>(&Hl[rl][ks * 32 + kg * 8]);
        }
#pragma unroll
        for (int nt = 0; nt < 4; ++nt) {
            const unsigned short* wb =
                Wlpk + (size_t)(((ks * 4 + nt) * 2)) * 512 + lane * 8;
            bf16x8 bh = *reinterpret_cast<const bf16x8*>(wb);
            bf16x8 blo = *reinterpret_cast<const bf16x8*>(wb + 512);
#pragma unroll
            for (int mt = 0; mt < 2; ++mt) {
                acc2[mt][nt] = __builtin_amdgcn_mfma_f32_16x16x32_bf16(ah[mt], bh,  acc2[mt][nt], 0, 0, 0);
                acc2[mt][nt] = __builtin_amdgcn_mfma_f32_16x16x32_bf16(ah[mt], blo, acc2[mt][nt], 0, 0, 0);
                acc2[mt][nt] = __builtin_amdgcn_mfma_f32_16x16x32_bf16(al[mt], bh,  acc2[mt][nt], 0, 0, 0);
            }
        }
    }

    // epilogue 2: out = (h2 + bl) * dg
#pragma unroll
    for (int mt = 0; mt < 2; ++mt)
#pragma unroll
        for (int nt = 0; nt < 4; ++nt) {
            int col = nt * 16 + r16;
            float bv = bl[col];
#pragma unroll
            for (int reg = 0; reg < 4; ++reg) {
                int rl = w * 32 + mt * 16 + kg * 4 + reg;
                if (m0 + rl < rowsEff) {
                    size_t idx = (size_t)(r0 + m0 + rl) * 64 + col;
                    outb[idx] = (acc2[mt][nt][reg] + bv) * dgb[idx];
                }
            }
        }
}

// ---------------------------------------------------------------------------
// pooling scatter: rank-translated compact read, one wave per nnz.
// ---------------------------------------------------------------------------
__global__ __launch_bounds__(256) void pool_scatter(
        const int* __restrict__ prow, const int* __restrict__ pcol,
        const float* __restrict__ pval, const int* __restrict__ poolRank,
        const float* __restrict__ outb, float* __restrict__ out) {
    int t = blockIdx.x * 256 + threadIdx.x;
    int i = t >> 6, d = t & 63;
    if (i >= NPERM_C) return;
    int r = prow[i], c = pcol[i];
    float v = pval[i];
    int cr = poolRank[c];
    atomicAdd(&out[(size_t)r * 64 + d], v * outb[(size_t)cr * 64 + d]);
}

extern "C" void kernel_launch(void* const* d_in, const int* in_sizes, int n_in,
                              void* d_out, int out_size, void* d_ws, size_t ws_size,
                              hipStream_t stream) {
    const float* x       = (const float*)d_in[0];
    const float* efeat   = (const float*)d_in[1];
    const float* degs    = (const float*)d_in[2];
    const int*   n2p_row = (const int*)d_in[3];
    const int*   n2p_col = (const int*)d_in[4];
    const float* n2p_val = (const float*)d_in[5];
    const int*   e2p_row = (const int*)d_in[6];
    const int*   e2p_col = (const int*)d_in[7];
    const float* e2p_val = (const float*)d_in[8];
    const int*   pool_row = (const int*)d_in[9];
    const int*   pool_col = (const int*)d_in[10];
    const float* pool_val = (const float*)d_in[11];
    const float* weights = (const float*)d_in[12];
    const float* bias    = (const float*)d_in[13];
    const float* W0      = (const float*)d_in[14];
    const float* b0      = (const float*)d_in[15];
    const float* W1      = (const float*)d_in[16];
    const float* b1      = (const float*)d_in[17];
    const float* Wl      = (const float*)d_in[18];
    const float* bl      = (const float*)d_in[19];
    float* out = (float*)d_out;

    // workspace layout (4B elems)
    uint2* suv      = (uint2*)d_ws;                    // 16,000,000
    int*   pOff     = (int*)(suv + 8000000);           //  4,000,064
    int*   pCur     = pOff + 4000064;                  //  4,000,000
    int*   bsum     = pCur + 4000000;                  //      2,048
    int*   poolCnt  = bsum + 2048;                     //    250,000
    int*   poolRank = poolCnt + 250000;                //    250,000
    int*   act      = poolRank + 250000;               //    250,000
    int*   bsum2    = act + 250000;                    //        256
    int*   nActB    = bsum2 + 256;                     //         16
    unsigned short* Bpk  = (unsigned short*)(nActB + 16);   // 131072 us = 65536
    unsigned short* Wlpk = Bpk + 131072;                    //   8192 us =  4096
    float* degD = (float*)(Wlpk + 8192);               //  1,000,000
    float* dgb  = degD + 1000000;                      // 16,000,000
    float* outb = dgb;                                 // alias (same-idx RAW)
    unsigned short* nfH = (unsigned short*)(dgb + 16000000);

    const long long base_elems = 16000000LL + 4000064 + 4000000 + 2048 +
                                 250000 * 3 + 256 + 16 + 65536 + 4096 +
                                 1000000 + 16000000;   // 41,822,016
    long long availf = (long long)(ws_size / 4) - base_elems;
    long long chl = availf / 1024;   // per row: 2 planes * 16*64 * 2B = 4 KB
    if (chl > NPERM_C) chl = NPERM_C;
    int CH = (int)(chl & ~127LL);
    if (CH < 128) {
        hipMemsetAsync(d_out, 0, (size_t)out_size * 4, stream);
        return;
    }
    unsigned short* nfL = nfH + (size_t)CH * 1024;

    hipMemsetAsync(pCur, 0, (size_t)P_C * 4, stream);
    hipMemsetAsync(poolCnt, 0, (size_t)NPERM_C * 4, stream);
    hipMemsetAsync(out, 0, (size_t)G_C * 64 * 4, stream);

    repack_bpk<<<512, 256, 0, stream>>>(weights, Bpk);
    repack_wlpk<<<32, 256, 0, stream>>>(Wl, Wlpk);

    pool_hist<<<(NPERM_C + 255) / 256, 256, 0, stream>>>(pool_col, poolCnt);
    pool_scan_local<<<NB2, 256, 0, stream>>>(poolCnt, poolRank, bsum2);
    pool_scan_top<<<1, 256, 0, stream>>>(bsum2);
    pool_scan_add<<<NB2, 256, 0, stream>>>(poolCnt, poolRank, bsum2, act, nActB);

    hist<<<31250, 256, 0, stream>>>(n2p_row, e2p_row, poolCnt, pCur);
    scan_local<<<NB1, 256, 0, stream>>>(pCur, pOff, bsum);
    scan_top<<<1, 256, 0, stream>>>(bsum);
    scan_add<<<NB1, 256, 0, stream>>>(pOff, bsum, pCur);
    scat<<<31250, 256, 0, stream>>>(n2p_row, n2p_col, n2p_val,
                                    e2p_row, e2p_col, e2p_val,
                                    poolCnt, pCur, suv);

    for (int c0 = 0; c0 < NPERM_C; c0 += CH) {
        int rows = NPERM_C - c0; if (rows > CH) rows = CH;
        gather_nfeat<<<(rows + 1) / 2, 256, 0, stream>>>(
            suv, pOff, x, efeat, degs, act, nActB, nfH, nfL, degD, c0, rows);
        dg_gemm<<<(rows + 63) / 64, 256, 0, stream>>>(
            degD, W0, b0, W1, b1, nActB, dgb, c0, rows);
        gemm_mfma<<<(rows + 127) / 128, 256, 0, stream>>>(
            nfH, nfL, Bpk, Wlpk, bias, bl, dgb, nActB, outb, c0, rows);
    }

    pool_scatter<<<62500, 256, 0, stream>>>(pool_row, pool_col, pool_val,
                                            poolRank, outb, out);
}